// Round 2
// baseline (506.291 us; speedup 1.0000x reference)
//
#include <hip/hip_runtime.h>

typedef float v2f __attribute__((ext_vector_type(2)));

#define IMG_W 512
#define IMG_H 512
#define RH    32            // output rows per block
#define BW    128           // output cols per block (one wave, 2 cols/lane)
#define KS    11
#define KR    5
#define OFF   8             // LDS left pad (>= KR, even)
#define LROW  (OFF + BW + OFF)   // 144 floats per row buffer

// One block = ONE WAVE (64 lanes x 2 cols = 128-col band, 32-row strip).
// Row pipeline: stage row in LDS -> packed horizontal 11-tap -> 11-row
// register ring -> packed vertical 11-tap + SSIM. Packing: {mu_a,mu_b} and
// {a^2,b^2} ride v_pk_fma_f32; barriers are intra-wave (cheap).
__global__ __launch_bounds__(64, 4)
void ssim_main(const float* __restrict__ xhat,
               const float* __restrict__ x,
               const float* __restrict__ kern,
               float* __restrict__ accum)
{
    __shared__ float rowA[LROW];   // a = (x+1)/2
    __shared__ float rowB[LROW];   // b = (xhat+1)/2

    const int lane  = threadIdx.x;
    const int band  = blockIdx.x & 3;           // 4 bands of 128 cols
    const int strip = (blockIdx.x >> 2) & 15;   // 16 strips of 32 rows
    const int img   = blockIdx.x >> 6;
    const int base  = band * BW;
    const int R0    = strip * RH;
    const float* xp = x    + (size_t)img * (IMG_W * IMG_H);
    const float* hp = xhat + (size_t)img * (IMG_W * IMG_H);

    // separable 1D weights from the rank-1 2D kernel
    float g[KS];
    {
        const float inv = rsqrtf(kern[5 * KS + 5]);
        #pragma unroll
        for (int i = 0; i < KS; ++i) g[i] = kern[5 * KS + i] * inv;
    }

    const int c0 = lane << 1;                    // local col of this lane
    const bool lhalo = lane < KR;                // stages col base-5+lane
    const bool rhalo = lane >= 64 - KR;          // stages col base+128+(lane-59)
    const int  lcol  = base - KR + lane;
    const int  rcol  = base + BW + lane - (64 - KR);

    // horizontal-conv ring: 11 rows x 2 cols, packed fields
    v2f   hist01[KS][2];   // {sum a, sum b}
    v2f   hist23[KS][2];   // {sum a^2, sum b^2}
    float hist4 [KS][2];   // sum a*b
    float acc = 0.f;
    const float C1 = 1e-4f, C2 = 9e-4f;

    #pragma unroll 1
    for (int rblk = 0; rblk < 44; rblk += 11) {
      #pragma unroll
      for (int p = 0; p < KS; ++p) {
        const int rr = rblk + p;
        const bool active = rr < RH + 2 * KR;    // < 42, wave-uniform

        __syncthreads();                          // intra-wave: cheap
        if (active) {
            const int ri  = R0 - KR + rr;
            const bool rok = (ri >= 0) && (ri < IMG_H);
            v2f av = {0.f, 0.f}, bv = {0.f, 0.f};
            float la = 0.f, lb = 0.f, ra = 0.f, rb = 0.f;
            if (rok) {
                const size_t roff = (size_t)ri * IMG_W;
                const float2 vx = *(const float2*)(xp + roff + base + c0);
                const float2 vh = *(const float2*)(hp + roff + base + c0);
                av.x = fmaf(vx.x, 0.5f, 0.5f); av.y = fmaf(vx.y, 0.5f, 0.5f);
                bv.x = fmaf(vh.x, 0.5f, 0.5f); bv.y = fmaf(vh.y, 0.5f, 0.5f);
                if (lhalo && lcol >= 0) {
                    la = fmaf(xp[roff + lcol], 0.5f, 0.5f);
                    lb = fmaf(hp[roff + lcol], 0.5f, 0.5f);
                }
                if (rhalo && rcol < IMG_W) {
                    ra = fmaf(xp[roff + rcol], 0.5f, 0.5f);
                    rb = fmaf(hp[roff + rcol], 0.5f, 0.5f);
                }
            }
            *(float2*)&rowA[OFF + c0] = make_float2(av.x, av.y);
            *(float2*)&rowB[OFF + c0] = make_float2(bv.x, bv.y);
            if (lhalo) { rowA[OFF - KR + lane] = la;
                         rowB[OFF - KR + lane] = lb; }
            if (rhalo) { rowA[OFF + BW + lane - (64 - KR)] = ra;
                         rowB[OFF + BW + lane - (64 - KR)] = rb; }
        }
        __syncthreads();

        if (active) {
            // ---- horizontal pass, packed over field pairs ----
            v2f h01[2] = {{0.f,0.f},{0.f,0.f}};
            v2f h23[2] = {{0.f,0.f},{0.f,0.f}};
            float h4[2] = {0.f, 0.f};
            const int ibase = OFF + c0 - KR;
            #pragma unroll
            for (int k = 0; k < KS + 1; ++k) {
                v2f ab;                       // {a, b} at window position k
                ab.x = rowA[ibase + k];
                ab.y = rowB[ibase + k];
                v2f  ab2 = ab * ab;           // {a^2, b^2}
                float pab = ab.x * ab.y;      // a*b
                if (k < KS) {                 // tap for col 0
                    const v2f w = {g[k], g[k]};
                    h01[0] = __builtin_elementwise_fma(ab,  w, h01[0]);
                    h23[0] = __builtin_elementwise_fma(ab2, w, h23[0]);
                    h4[0]  = fmaf(pab, g[k], h4[0]);
                }
                if (k > 0) {                  // tap for col 1
                    const v2f w = {g[k-1], g[k-1]};
                    h01[1] = __builtin_elementwise_fma(ab,  w, h01[1]);
                    h23[1] = __builtin_elementwise_fma(ab2, w, h23[1]);
                    h4[1]  = fmaf(pab, g[k-1], h4[1]);
                }
            }
            #pragma unroll
            for (int c = 0; c < 2; ++c) {
                hist01[p][c] = h01[c];
                hist23[p][c] = h23[c];
                hist4 [p][c] = h4[c];
            }

            // ---- vertical pass + SSIM once the ring is full ----
            if (rr >= 2 * KR) {
                v2f v01[2] = {{0.f,0.f},{0.f,0.f}};
                v2f v23[2] = {{0.f,0.f},{0.f,0.f}};
                float v4[2] = {0.f, 0.f};
                #pragma unroll
                for (int t = 0; t < KS; ++t) {
                    const int slot = (p + 1 + t) % KS;  // compile-time
                    const v2f w = {g[t], g[t]};
                    #pragma unroll
                    for (int c = 0; c < 2; ++c) {
                        v01[c] = __builtin_elementwise_fma(hist01[slot][c], w, v01[c]);
                        v23[c] = __builtin_elementwise_fma(hist23[slot][c], w, v23[c]);
                        v4[c]  = fmaf(hist4[slot][c], g[t], v4[c]);
                    }
                }
                #pragma unroll
                for (int c = 0; c < 2; ++c) {
                    const float mux  = v01[c].x, muy = v01[c].y;
                    const float mux2 = mux * mux;
                    const float muy2 = muy * muy;
                    const float muxy = mux * muy;
                    const float sx   = v23[c].x - mux2;
                    const float sy   = v23[c].y - muy2;
                    const float sxy  = v4[c]    - muxy;
                    const float num  = (2.f * muxy + C1) * (2.f * sxy + C2);
                    const float den  = (mux2 + muy2 + C1) * (sx + sy + C2);
                    acc += num / (den + 1e-8f);
                }
            }
        }
      }
    }

    // single-wave block: shuffle reduce, one atomic
    #pragma unroll
    for (int o = 32; o > 0; o >>= 1) acc += __shfl_down(acc, o, 64);
    if (lane == 0) atomicAdd(accum, acc);
}

__global__ void ssim_final(const float* __restrict__ accum,
                           float* __restrict__ out)
{
    out[0] = 1.0f - accum[0] * (1.0f / (64.0f * 512.0f * 512.0f));
}

extern "C" void kernel_launch(void* const* d_in, const int* in_sizes, int n_in,
                              void* d_out, int out_size, void* d_ws, size_t ws_size,
                              hipStream_t stream) {
    const float* xhat = (const float*)d_in[0];
    const float* xin  = (const float*)d_in[1];
    const float* kern = (const float*)d_in[2];
    float* out = (float*)d_out;
    float* ws  = (float*)d_ws;

    const int nimg   = in_sizes[0] / (IMG_W * IMG_H);     // 64
    const int nblk   = nimg * (IMG_H / RH) * (IMG_W / BW); // 64*16*4 = 4096

    hipMemsetAsync(ws, 0, sizeof(float), stream);
    ssim_main<<<nblk, 64, 0, stream>>>(xhat, xin, kern, ws);
    ssim_final<<<1, 1, 0, stream>>>(ws, out);
}

// Round 3
// 234.896 us; speedup vs baseline: 2.1554x; 2.1554x over previous
//
#include <hip/hip_runtime.h>

typedef float v2f __attribute__((ext_vector_type(2)));

#define IMG_W 512
#define IMG_H 512
#define RH    64            // output rows per block
#define BW    128           // output cols per block (one wave, 2 cols/lane)
#define KS    11
#define KR    5
#define OFFP  9             // left pad in PAIRS; odd => window reads 16B-aligned
#define LROWP (OFFP + BW + OFFP)     // 146 {a,b} pairs per row buffer
#define ROWS  (RH + 2 * KR)          // 74 input rows per strip
#define NPH   77                     // 7 * 11 phases (>= ROWS+2)

// per-row prefetch registers (raw -> transformed at load time; zeros = conv pad)
struct Pf { float ax, ay, bx, by, lx, lb, rx, rb; };

// One block = ONE WAVE: 64 lanes x 2 cols = 128-col band, 64-row strip.
// Row pipeline: ds_write staged {a,b} pairs -> s_waitcnt lgkmcnt(0) (wave-
// synchronous, no vmcnt drain) -> issue global prefetch for row rr+2 ->
// 6x ds_read_b128 window -> packed horizontal taps -> 11-row register ring
// -> packed vertical taps + SSIM. Ring lives in the unified VGPR/AGPR file:
// launch_bounds(64,2) gives a 256-reg budget (round 2's (64,4) caused the
// 1.16 GB/launch scratch-spill catastrophe).
__global__ __launch_bounds__(64, 2)
void ssim_main(const float* __restrict__ xhat,
               const float* __restrict__ x,
               const float* __restrict__ kern,
               float* __restrict__ accum)
{
    __shared__ float lds[2][2 * LROWP];   // ping-pong row buffers, 2.3 KB

    const int lane  = threadIdx.x;
    const int band  = blockIdx.x & 3;           // 4 bands of 128 cols
    const int strip = (blockIdx.x >> 2) & 7;    // 8 strips of 64 rows
    const int img   = blockIdx.x >> 5;
    const int base  = band * BW;
    const int R0    = strip * RH;
    const float* xp = x    + (size_t)img * (IMG_W * IMG_H);
    const float* hp = xhat + (size_t)img * (IMG_W * IMG_H);

    // separable 1D weights from the rank-1 2D kernel
    float g[KS];
    {
        const float inv = rsqrtf(kern[5 * KS + 5]);
        #pragma unroll
        for (int i = 0; i < KS; ++i) g[i] = kern[5 * KS + i] * inv;
    }

    const int  c0   = lane << 1;
    const bool lh   = lane < KR;
    const bool rhn  = lane >= 64 - KR;
    const int  lcol = base - KR + lane;                 // lh lanes
    const int  rcol = base + BW + (lane - (64 - KR));   // rhn lanes
    const int  lidx = OFFP - KR + lane;                 // pair idx 4..8
    const int  ridx = OFFP + BW + (lane - (64 - KR));   // pair idx 137..141

    auto load_row = [&](int rr) -> Pf {
        Pf p = {0.f,0.f,0.f,0.f,0.f,0.f,0.f,0.f};
        const int ri = R0 - KR + rr;
        if (ri >= 0 && ri < IMG_H) {
            const size_t ro = (size_t)ri * IMG_W;
            const float2 vx = *(const float2*)(xp + ro + base + c0);
            const float2 vh = *(const float2*)(hp + ro + base + c0);
            p.ax = fmaf(vx.x, 0.5f, 0.5f);  p.ay = fmaf(vx.y, 0.5f, 0.5f);
            p.bx = fmaf(vh.x, 0.5f, 0.5f);  p.by = fmaf(vh.y, 0.5f, 0.5f);
            if (lh && lcol >= 0) {
                p.lx = fmaf(xp[ro + lcol], 0.5f, 0.5f);
                p.lb = fmaf(hp[ro + lcol], 0.5f, 0.5f);
            }
            if (rhn && rcol < IMG_W) {
                p.rx = fmaf(xp[ro + rcol], 0.5f, 0.5f);
                p.rb = fmaf(hp[ro + rcol], 0.5f, 0.5f);
            }
        }
        return p;
    };

    // ring of horizontally-convolved rows: 5 fields x 11 rows x 2 cols
    v2f   h01r[KS][2];   // {sum a, sum b}
    v2f   h23r[KS][2];   // {sum a^2, sum b^2}
    float h4r [KS][2];   // sum a*b
    float acc = 0.f;
    const float C1 = 1e-4f, C2 = 9e-4f;

    Pf pfA = load_row(0);             // even rows of current outer iter
    Pf pfB = load_row(1);             // odd rows
    float* bufA = lds[0];
    float* bufB = lds[1];

    #pragma unroll 1
    for (int rblk = 0; rblk < NPH; rblk += KS) {
        #pragma unroll
        for (int p = 0; p < KS; ++p) {
            const int rr = rblk + p;            // ring slot == p (11 | rblk)
            if (rr < ROWS) {                    // wave-uniform branch
                constexpr bool evenp = true;    // p parity resolved below
                Pf&    cur = ((p & 1) == 0) ? pfA : pfB;
                float* buf = ((p & 1) == 0) ? bufA : bufB;

                // ---- stage row rr (two b64 writes + predicated halo) ----
                *(float2*)&buf[2 * (OFFP + c0)]     = make_float2(cur.ax, cur.bx);
                *(float2*)&buf[2 * (OFFP + c0) + 2] = make_float2(cur.ay, cur.by);
                if (lh)  *(float2*)&buf[2 * lidx] = make_float2(cur.lx, cur.lb);
                if (rhn) *(float2*)&buf[2 * ridx] = make_float2(cur.rx, cur.rb);
                __asm__ __volatile__("s_waitcnt lgkmcnt(0)" ::: "memory");

                // ---- prefetch row rr+2 into the slot just consumed ----
                if (rr + 2 < ROWS) cur = load_row(rr + 2);

                // ---- horizontal pass: 6x ds_read_b128 window ----
                const float4* q = (const float4*)buf;
                const int qb = lane + (OFFP - KR) / 2;   // (2*lane+4)/2
                float4 w[6];
                #pragma unroll
                for (int j = 0; j < 6; ++j) w[j] = q[qb + j];

                v2f h01[2] = {{0.f,0.f},{0.f,0.f}};
                v2f h23[2] = {{0.f,0.f},{0.f,0.f}};
                float h4[2] = {0.f, 0.f};
                #pragma unroll
                for (int t = 0; t < KS + 1; ++t) {
                    v2f ab;
                    ab.x = (t & 1) ? w[t >> 1].z : w[t >> 1].x;
                    ab.y = (t & 1) ? w[t >> 1].w : w[t >> 1].y;
                    const v2f  ab2 = ab * ab;
                    const float pab = ab.x * ab.y;
                    if (t < KS) {                 // tap for col 0
                        const v2f wv = {g[t], g[t]};
                        h01[0] = __builtin_elementwise_fma(ab,  wv, h01[0]);
                        h23[0] = __builtin_elementwise_fma(ab2, wv, h23[0]);
                        h4[0]  = fmaf(pab, g[t], h4[0]);
                    }
                    if (t > 0) {                  // tap for col 1
                        const v2f wv = {g[t - 1], g[t - 1]};
                        h01[1] = __builtin_elementwise_fma(ab,  wv, h01[1]);
                        h23[1] = __builtin_elementwise_fma(ab2, wv, h23[1]);
                        h4[1]  = fmaf(pab, g[t - 1], h4[1]);
                    }
                }
                #pragma unroll
                for (int c = 0; c < 2; ++c) {
                    h01r[p][c] = h01[c];
                    h23r[p][c] = h23[c];
                    h4r [p][c] = h4[c];
                }

                // ---- vertical pass + SSIM once the ring is full ----
                if (rr >= 2 * KR) {
                    v2f v01[2] = {{0.f,0.f},{0.f,0.f}};
                    v2f v23[2] = {{0.f,0.f},{0.f,0.f}};
                    float v4[2] = {0.f, 0.f};
                    #pragma unroll
                    for (int t = 0; t < KS; ++t) {
                        const int slot = (p + 1 + t) % KS;   // compile-time
                        const v2f wv = {g[t], g[t]};
                        #pragma unroll
                        for (int c = 0; c < 2; ++c) {
                            v01[c] = __builtin_elementwise_fma(h01r[slot][c], wv, v01[c]);
                            v23[c] = __builtin_elementwise_fma(h23r[slot][c], wv, v23[c]);
                            v4[c]  = fmaf(h4r[slot][c], g[t], v4[c]);
                        }
                    }
                    #pragma unroll
                    for (int c = 0; c < 2; ++c) {
                        const float mux  = v01[c].x, muy = v01[c].y;
                        const float mux2 = mux * mux;
                        const float muy2 = muy * muy;
                        const float muxy = mux * muy;
                        const float sx   = v23[c].x - mux2;
                        const float sy   = v23[c].y - muy2;
                        const float sxy  = v4[c]    - muxy;
                        const float num  = (2.f * muxy + C1) * (2.f * sxy + C2);
                        const float den  = (mux2 + muy2 + C1) * (sx + sy + C2);
                        acc = fmaf(num, __builtin_amdgcn_rcpf(den + 1e-8f), acc);
                    }
                }
            }
        }
        // 11 phases consumed (odd count): swap even/odd roles
        { Pf t = pfA; pfA = pfB; pfB = t; }
        { float* t = bufA; bufA = bufB; bufB = t; }
    }

    // single-wave block: shuffle reduce, one atomic per block
    #pragma unroll
    for (int o = 32; o > 0; o >>= 1) acc += __shfl_down(acc, o, 64);
    if (lane == 0) atomicAdd(accum, acc);
}

__global__ void ssim_final(const float* __restrict__ accum,
                           float* __restrict__ out)
{
    out[0] = 1.0f - accum[0] * (1.0f / (64.0f * 512.0f * 512.0f));
}

extern "C" void kernel_launch(void* const* d_in, const int* in_sizes, int n_in,
                              void* d_out, int out_size, void* d_ws, size_t ws_size,
                              hipStream_t stream) {
    const float* xhat = (const float*)d_in[0];
    const float* xin  = (const float*)d_in[1];
    const float* kern = (const float*)d_in[2];
    float* out = (float*)d_out;
    float* ws  = (float*)d_ws;

    const int nimg = in_sizes[0] / (IMG_W * IMG_H);          // 64
    const int nblk = nimg * (IMG_H / RH) * (IMG_W / BW);     // 64*8*4 = 2048

    hipMemsetAsync(ws, 0, sizeof(float), stream);
    ssim_main<<<nblk, 64, 0, stream>>>(xhat, xin, kern, ws);
    ssim_final<<<1, 1, 0, stream>>>(ws, out);
}

// Round 4
// 231.934 us; speedup vs baseline: 2.1829x; 1.0128x over previous
//
#include <hip/hip_runtime.h>

typedef float v2f __attribute__((ext_vector_type(2)));

#define IMG_W 512
#define IMG_H 512
#define RH    32            // output rows per block
#define BW    128           // output cols per block (one wave, 2 cols/lane)
#define KS    11
#define KR    5
#define OFFP  9             // left pad in PAIRS; odd => 16B-aligned b128 window
#define LROWP (OFFP + BW + OFFP)     // 146 {a,b} pairs per row buffer
#define ROWS  (RH + 2 * KR)          // 42 input rows per strip
#define NPH   44                     // 4 * 11 phases (>= ROWS)

// per-row prefetch registers: RAW pixel values. Out-of-bounds lanes/rows hold
// -1.0f, which the staging transform fmaf(v,0.5,0.5) maps to exactly 0.0f ==
// the conv zero-padding. Keeping the prefetch raw means no VALU op depends on
// the in-flight global loads at issue time.
struct Pf { float ax, ay, bx, by, lx, lb, rx, rb; };

// One block = ONE WAVE: 64 lanes x 2 cols = 128-col band, 32-row strip.
// 4096 blocks -> 16 waves/CU (4/SIMD at VGPR<=128) for latency hiding; round 3
// (RH=64, 2048 blocks) measured Occupancy 18.7% / VALUBusy 41% -- grid-starved.
// Phase: transform+ds_write row rr -> issue raw global prefetch rr+2 ->
// s_waitcnt lgkmcnt(0) (wave-sync; does NOT drain vmcnt, prefetch stays in
// flight) -> 6x ds_read_b128 window -> packed horizontal taps -> 11-row
// register ring -> packed vertical taps + SSIM.
__global__ __launch_bounds__(64, 2)
void ssim_main(const float* __restrict__ xhat,
               const float* __restrict__ x,
               const float* __restrict__ kern,
               float* __restrict__ accum)
{
    __shared__ __align__(16) float lds[2][2 * LROWP];  // ping-pong, 2.3 KB

    const int lane  = threadIdx.x;
    const int band  = blockIdx.x & 3;           // 4 bands of 128 cols
    const int strip = (blockIdx.x >> 2) & 15;   // 16 strips of 32 rows
    const int img   = blockIdx.x >> 6;
    const int base  = band * BW;
    const int R0    = strip * RH;
    const float* xp = x    + (size_t)img * (IMG_W * IMG_H);
    const float* hp = xhat + (size_t)img * (IMG_W * IMG_H);

    // separable 1D weights from the rank-1 2D kernel
    float g[KS];
    {
        const float inv = rsqrtf(kern[5 * KS + 5]);
        #pragma unroll
        for (int i = 0; i < KS; ++i) g[i] = kern[5 * KS + i] * inv;
    }

    const int  c0   = lane << 1;
    const bool lh   = lane < KR;
    const bool rhn  = lane >= 64 - KR;
    const int  lcol = base - KR + lane;                 // lh lanes
    const int  rcol = base + BW + (lane - (64 - KR));   // rhn lanes
    const int  lidx = OFFP - KR + lane;                 // pair idx 4..8
    const int  ridx = OFFP + BW + (lane - (64 - KR));   // pair idx 137..141

    auto load_raw = [&](int rr) -> Pf {
        Pf p = {-1.f,-1.f,-1.f,-1.f,-1.f,-1.f,-1.f,-1.f};
        const int ri = R0 - KR + rr;
        if (ri >= 0 && ri < IMG_H) {
            const size_t ro = (size_t)ri * IMG_W;
            const float2 vx = *(const float2*)(xp + ro + base + c0);
            const float2 vh = *(const float2*)(hp + ro + base + c0);
            p.ax = vx.x;  p.ay = vx.y;
            p.bx = vh.x;  p.by = vh.y;
            if (lh && lcol >= 0) {
                p.lx = xp[ro + lcol];
                p.lb = hp[ro + lcol];
            }
            if (rhn && rcol < IMG_W) {
                p.rx = xp[ro + rcol];
                p.rb = hp[ro + rcol];
            }
        }
        return p;
    };

    // ring of horizontally-convolved rows: 5 fields x 11 rows x 2 cols
    v2f   h01r[KS][2];   // {sum a, sum b}
    v2f   h23r[KS][2];   // {sum a^2, sum b^2}
    float h4r [KS][2];   // sum a*b
    float acc = 0.f;
    const float C1 = 1e-4f, C2 = 9e-4f;

    Pf pfA = load_raw(0);             // even phases of current outer iter
    Pf pfB = load_raw(1);             // odd phases
    float* bufA = lds[0];
    float* bufB = lds[1];

    #pragma unroll 1
    for (int rblk = 0; rblk < NPH; rblk += KS) {
        #pragma unroll
        for (int p = 0; p < KS; ++p) {
            const int rr = rblk + p;            // ring slot == p (11 | rblk)
            if (rr < ROWS) {                    // wave-uniform branch
                Pf&    cur = ((p & 1) == 0) ? pfA : pfB;
                float* buf = ((p & 1) == 0) ? bufA : bufB;

                // ---- stage row rr: raw -> (v+1)/2, interleaved {a,b} ----
                *(float2*)&buf[2 * (OFFP + c0)] =
                    make_float2(fmaf(cur.ax, 0.5f, 0.5f), fmaf(cur.bx, 0.5f, 0.5f));
                *(float2*)&buf[2 * (OFFP + c0) + 2] =
                    make_float2(fmaf(cur.ay, 0.5f, 0.5f), fmaf(cur.by, 0.5f, 0.5f));
                if (lh)  *(float2*)&buf[2 * lidx] =
                    make_float2(fmaf(cur.lx, 0.5f, 0.5f), fmaf(cur.lb, 0.5f, 0.5f));
                if (rhn) *(float2*)&buf[2 * ridx] =
                    make_float2(fmaf(cur.rx, 0.5f, 0.5f), fmaf(cur.rb, 0.5f, 0.5f));

                // ---- issue raw global prefetch for row rr+2 (in flight
                //      across the LDS wait below: lgkm != vm counter) ----
                const bool hasNext = (rr + 2 < ROWS);
                Pf nxt;
                if (hasNext) nxt = load_raw(rr + 2);

                __asm__ __volatile__("s_waitcnt lgkmcnt(0)" ::: "memory");

                // ---- horizontal pass: 6x ds_read_b128 window ----
                const float4* q = (const float4*)buf;
                float4 w[6];
                #pragma unroll
                for (int j = 0; j < 6; ++j) w[j] = q[lane + 2 + j];

                v2f h01[2] = {{0.f,0.f},{0.f,0.f}};
                v2f h23[2] = {{0.f,0.f},{0.f,0.f}};
                float h4[2] = {0.f, 0.f};
                #pragma unroll
                for (int t = 0; t < KS + 1; ++t) {
                    v2f ab;
                    ab.x = (t & 1) ? w[t >> 1].z : w[t >> 1].x;
                    ab.y = (t & 1) ? w[t >> 1].w : w[t >> 1].y;
                    const v2f  ab2 = ab * ab;
                    const float pab = ab.x * ab.y;
                    if (t < KS) {                 // tap for col 0
                        const v2f wv = {g[t], g[t]};
                        h01[0] = __builtin_elementwise_fma(ab,  wv, h01[0]);
                        h23[0] = __builtin_elementwise_fma(ab2, wv, h23[0]);
                        h4[0]  = fmaf(pab, g[t], h4[0]);
                    }
                    if (t > 0) {                  // tap for col 1
                        const v2f wv = {g[t - 1], g[t - 1]};
                        h01[1] = __builtin_elementwise_fma(ab,  wv, h01[1]);
                        h23[1] = __builtin_elementwise_fma(ab2, wv, h23[1]);
                        h4[1]  = fmaf(pab, g[t - 1], h4[1]);
                    }
                }
                #pragma unroll
                for (int c = 0; c < 2; ++c) {
                    h01r[p][c] = h01[c];
                    h23r[p][c] = h23[c];
                    h4r [p][c] = h4[c];
                }

                // ---- vertical pass + SSIM once the ring is full ----
                if (rr >= 2 * KR) {
                    v2f v01[2] = {{0.f,0.f},{0.f,0.f}};
                    v2f v23[2] = {{0.f,0.f},{0.f,0.f}};
                    float v4[2] = {0.f, 0.f};
                    #pragma unroll
                    for (int t = 0; t < KS; ++t) {
                        const int slot = (p + 1 + t) % KS;   // compile-time
                        const v2f wv = {g[t], g[t]};
                        #pragma unroll
                        for (int c = 0; c < 2; ++c) {
                            v01[c] = __builtin_elementwise_fma(h01r[slot][c], wv, v01[c]);
                            v23[c] = __builtin_elementwise_fma(h23r[slot][c], wv, v23[c]);
                            v4[c]  = fmaf(h4r[slot][c], g[t], v4[c]);
                        }
                    }
                    #pragma unroll
                    for (int c = 0; c < 2; ++c) {
                        const float mux  = v01[c].x, muy = v01[c].y;
                        const float mux2 = mux * mux;
                        const float muy2 = muy * muy;
                        const float muxy = mux * muy;
                        const float sx   = v23[c].x - mux2;
                        const float sy   = v23[c].y - muy2;
                        const float sxy  = v4[c]    - muxy;
                        const float num  = (2.f * muxy + C1) * (2.f * sxy + C2);
                        const float den  = (mux2 + muy2 + C1) * (sx + sy + C2);
                        acc = fmaf(num, __builtin_amdgcn_rcpf(den + 1e-8f), acc);
                    }
                }

                if (hasNext) cur = nxt;           // commit prefetch
            }
        }
        // 11 phases consumed (odd count): swap even/odd roles
        { Pf t = pfA; pfA = pfB; pfB = t; }
        { float* t = bufA; bufA = bufB; bufB = t; }
    }

    // single-wave block: shuffle reduce, one atomic per block
    #pragma unroll
    for (int o = 32; o > 0; o >>= 1) acc += __shfl_down(acc, o, 64);
    if (lane == 0) atomicAdd(accum, acc);
}

__global__ void ssim_final(const float* __restrict__ accum,
                           float* __restrict__ out)
{
    out[0] = 1.0f - accum[0] * (1.0f / (64.0f * 512.0f * 512.0f));
}

extern "C" void kernel_launch(void* const* d_in, const int* in_sizes, int n_in,
                              void* d_out, int out_size, void* d_ws, size_t ws_size,
                              hipStream_t stream) {
    const float* xhat = (const float*)d_in[0];
    const float* xin  = (const float*)d_in[1];
    const float* kern = (const float*)d_in[2];
    float* out = (float*)d_out;
    float* ws  = (float*)d_ws;

    const int nimg = in_sizes[0] / (IMG_W * IMG_H);          // 64
    const int nblk = nimg * (IMG_H / RH) * (IMG_W / BW);     // 64*16*4 = 4096

    hipMemsetAsync(ws, 0, sizeof(float), stream);
    ssim_main<<<nblk, 64, 0, stream>>>(xhat, xin, kern, ws);
    ssim_final<<<1, 1, 0, stream>>>(ws, out);
}